// Round 7
// baseline (798.402 us; speedup 1.0000x reference)
//
#include <hip/hip_runtime.h>

typedef unsigned short u16;
typedef __bf16 bf16x8 __attribute__((ext_vector_type(8)));
typedef float f32x4 __attribute__((ext_vector_type(4)));
typedef unsigned short u16x8 __attribute__((ext_vector_type(8)));
typedef unsigned short u16x4 __attribute__((ext_vector_type(4)));

__device__ __forceinline__ u16 f2bf(float f) {
    unsigned u = __builtin_bit_cast(unsigned, f);
    u += 0x7FFFu + ((u >> 16) & 1u);   // RNE
    return (u16)(u >> 16);
}
__device__ __forceinline__ float bf2f(u16 s) {
    return __builtin_bit_cast(float, ((unsigned)s) << 16);
}

// Stage 8 contiguous elements into LDS as bf16 (single precision level).
__device__ __forceinline__ void stage8(u16* dst, const u16* src) {
    *(u16x8*)dst = *(const u16x8*)src;
}
__device__ __forceinline__ void stage8(u16* dst, const float* src) {
    float4 a = *(const float4*)src;
    float4 b = *(const float4*)(src + 4);
    u16x8 v;
    v[0] = f2bf(a.x); v[1] = f2bf(a.y); v[2] = f2bf(a.z); v[3] = f2bf(a.w);
    v[4] = f2bf(b.x); v[5] = f2bf(b.y); v[6] = f2bf(b.z); v[7] = f2bf(b.w);
    *(u16x8*)dst = v;
}

// Stage 8 fp32 elements as hi/lo bf16 pair: a = hi + lo + O(2^-17 a)
__device__ __forceinline__ void stage8_split(u16* dh, u16* dl, const float* src) {
    float4 a = *(const float4*)src;
    float4 b = *(const float4*)(src + 4);
    float v[8] = {a.x, a.y, a.z, a.w, b.x, b.y, b.z, b.w};
    u16x8 hi, lo;
#pragma unroll
    for (int j = 0; j < 8; ++j) {
        u16 h = f2bf(v[j]);
        hi[j] = h;
        lo[j] = f2bf(v[j] - bf2f(h));
    }
    *(u16x8*)dh = hi;
    *(u16x8*)dl = lo;
}

#define BM 128
#define BN 128
#define BK 32
#define LDS_STRIDE 40   // 32 + 8 pad shorts -> 80B row stride, 16B aligned

// ---------- single-precision-level bf16 GEMM: C = A * B^T (+bias) ----------
// A-frag lane holds A[m=lane&15][k=quad*8+j]; B-frag symmetric.
// C/D: col=lane&15, row=quad*4+reg (m89-verified).
template<typename TA, typename TB, bool OUTF32>
__global__ void gemm_nt(const TA* __restrict__ A, const TB* __restrict__ B,
                        const float* __restrict__ bias, void* __restrict__ C,
                        int K, long long lda, long long ldb, long long ldc)
{
    __shared__ u16 As[BM * LDS_STRIDE];
    __shared__ u16 Bs[BN * LDS_STRIDE];
    const int t = threadIdx.x;
    const int wave = t >> 6, lane = t & 63, quad = lane >> 4, l16 = lane & 15;
    const int waveM = (wave & 1) * 64, waveN = (wave >> 1) * 64;
    const long long rowBase = (long long)blockIdx.y * BM;
    const long long colBase = (long long)blockIdx.x * BN;
    A += rowBase * lda;
    B += colBase * ldb;

    f32x4 acc[4][4];
#pragma unroll
    for (int i = 0; i < 4; ++i)
#pragma unroll
        for (int j = 0; j < 4; ++j) acc[i][j] = (f32x4){0.f, 0.f, 0.f, 0.f};

    for (int k0 = 0; k0 < K; k0 += BK) {
        __syncthreads();
#pragma unroll
        for (int i = 0; i < 2; ++i) {
            int seg = t + i * 256;          // 512 segments of 8 elems = 128x32 tile
            int r = seg >> 2;
            int c = (seg & 3) << 3;
            stage8(&As[r * LDS_STRIDE + c], A + (long long)r * lda + k0 + c);
            stage8(&Bs[r * LDS_STRIDE + c], B + (long long)r * ldb + k0 + c);
        }
        __syncthreads();

        bf16x8 af[4], bfr[4];
#pragma unroll
        for (int mi = 0; mi < 4; ++mi)
            af[mi] = __builtin_bit_cast(bf16x8,
                *(const u16x8*)(&As[(waveM + mi * 16 + l16) * LDS_STRIDE + quad * 8]));
#pragma unroll
        for (int ni = 0; ni < 4; ++ni)
            bfr[ni] = __builtin_bit_cast(bf16x8,
                *(const u16x8*)(&Bs[(waveN + ni * 16 + l16) * LDS_STRIDE + quad * 8]));
#pragma unroll
        for (int mi = 0; mi < 4; ++mi)
#pragma unroll
            for (int ni = 0; ni < 4; ++ni)
                acc[mi][ni] = __builtin_amdgcn_mfma_f32_16x16x32_bf16(af[mi], bfr[ni], acc[mi][ni], 0, 0, 0);
    }

#pragma unroll
    for (int mi = 0; mi < 4; ++mi) {
#pragma unroll
        for (int ni = 0; ni < 4; ++ni) {
            long long col = colBase + waveN + ni * 16 + l16;
            float bv = bias ? bias[col] : 0.0f;
#pragma unroll
            for (int r = 0; r < 4; ++r) {
                long long row = rowBase + waveM + mi * 16 + quad * 4 + r;
                float f = acc[mi][ni][r] + bv;
                long long off = row * ldc + col;
                if (OUTF32) ((float*)C)[off] = f;
                else        ((u16*)C)[off] = f2bf(f);
            }
        }
    }
}

// ---------- split-bf16 emulated-fp32 GEMM: C = A * B^T (+bias), fp32 out ----
// a*b ~= a_hi*b_hi + a_hi*b_lo + a_lo*b_hi  (per-term rel err ~2^-17)
__global__ void gemm_nt3(const float* __restrict__ A, const float* __restrict__ B,
                         const float* __restrict__ bias, float* __restrict__ C,
                         int K, long long lda, long long ldb, long long ldc)
{
    __shared__ u16 Ah[BM * LDS_STRIDE];
    __shared__ u16 Al[BM * LDS_STRIDE];
    __shared__ u16 Bh[BN * LDS_STRIDE];
    __shared__ u16 Bl[BN * LDS_STRIDE];
    const int t = threadIdx.x;
    const int wave = t >> 6, lane = t & 63, quad = lane >> 4, l16 = lane & 15;
    const int waveM = (wave & 1) * 64, waveN = (wave >> 1) * 64;
    const long long rowBase = (long long)blockIdx.y * BM;
    const long long colBase = (long long)blockIdx.x * BN;
    A += rowBase * lda;
    B += colBase * ldb;

    f32x4 acc[4][4];
#pragma unroll
    for (int i = 0; i < 4; ++i)
#pragma unroll
        for (int j = 0; j < 4; ++j) acc[i][j] = (f32x4){0.f, 0.f, 0.f, 0.f};

    for (int k0 = 0; k0 < K; k0 += BK) {
        __syncthreads();
#pragma unroll
        for (int i = 0; i < 2; ++i) {
            int seg = t + i * 256;
            int r = seg >> 2;
            int c = (seg & 3) << 3;
            stage8_split(&Ah[r * LDS_STRIDE + c], &Al[r * LDS_STRIDE + c],
                         A + (long long)r * lda + k0 + c);
            stage8_split(&Bh[r * LDS_STRIDE + c], &Bl[r * LDS_STRIDE + c],
                         B + (long long)r * ldb + k0 + c);
        }
        __syncthreads();

        bf16x8 ah[4], al[4], bh[4], bl[4];
#pragma unroll
        for (int mi = 0; mi < 4; ++mi) {
            int off = (waveM + mi * 16 + l16) * LDS_STRIDE + quad * 8;
            ah[mi] = __builtin_bit_cast(bf16x8, *(const u16x8*)(&Ah[off]));
            al[mi] = __builtin_bit_cast(bf16x8, *(const u16x8*)(&Al[off]));
        }
#pragma unroll
        for (int ni = 0; ni < 4; ++ni) {
            int off = (waveN + ni * 16 + l16) * LDS_STRIDE + quad * 8;
            bh[ni] = __builtin_bit_cast(bf16x8, *(const u16x8*)(&Bh[off]));
            bl[ni] = __builtin_bit_cast(bf16x8, *(const u16x8*)(&Bl[off]));
        }
#pragma unroll
        for (int mi = 0; mi < 4; ++mi)
#pragma unroll
            for (int ni = 0; ni < 4; ++ni) {
                acc[mi][ni] = __builtin_amdgcn_mfma_f32_16x16x32_bf16(al[mi], bh[ni], acc[mi][ni], 0, 0, 0);
                acc[mi][ni] = __builtin_amdgcn_mfma_f32_16x16x32_bf16(ah[mi], bl[ni], acc[mi][ni], 0, 0, 0);
                acc[mi][ni] = __builtin_amdgcn_mfma_f32_16x16x32_bf16(ah[mi], bh[ni], acc[mi][ni], 0, 0, 0);
            }
    }

#pragma unroll
    for (int mi = 0; mi < 4; ++mi) {
#pragma unroll
        for (int ni = 0; ni < 4; ++ni) {
            long long col = colBase + waveN + ni * 16 + l16;
            float bv = bias ? bias[col] : 0.0f;
#pragma unroll
            for (int r = 0; r < 4; ++r) {
                long long row = rowBase + waveM + mi * 16 + quad * 4 + r;
                C[row * ldc + col] = acc[mi][ni][r] + bv;
            }
        }
    }
}

// src [4096,512] fp32 -> dst [512,4096] bf16 (one batch)
__global__ void transpose_mem(const float* __restrict__ src, u16* __restrict__ dst)
{
    __shared__ u16 tile[64][72];
    const int dBase = blockIdx.x * 64, mBase = blockIdx.y * 64;
    const int t = threadIdx.x;
#pragma unroll
    for (int i = 0; i < 4; ++i) {
        int seg = t + i * 256;            // 1024 segments of 4 floats = 64x64 tile
        int r = seg >> 4;                 // m-local
        int c = (seg & 15) << 2;          // d-local
        float4 v = *(const float4*)(src + (long long)(mBase + r) * 512 + dBase + c);
        tile[r][c]     = f2bf(v.x);
        tile[r][c + 1] = f2bf(v.y);
        tile[r][c + 2] = f2bf(v.z);
        tile[r][c + 3] = f2bf(v.w);
    }
    __syncthreads();
#pragma unroll
    for (int i = 0; i < 2; ++i) {
        int seg = t + i * 256;
        int r = seg >> 3;          // d-local
        int c = (seg & 7) << 3;    // m-local
        u16x8 v;
#pragma unroll
        for (int j = 0; j < 8; ++j) v[j] = tile[c + j][r];
        *(u16x8*)(dst + (long long)(dBase + r) * 4096 + mBase + c) = v;
    }
}

// One block per row of 4096 fp32 scores; writes normalized bf16 weights in place
// (first 8KB of the row's 16KB slot; row stride stays 8192 u16).
__global__ void softmax_rows(float* __restrict__ S)
{
    float* p = S + (long long)blockIdx.x * 4096;
    const int t = threadIdx.x;
    float4 v[4];
#pragma unroll
    for (int i = 0; i < 4; ++i) v[i] = ((const float4*)p)[t + i * 256];

    float m = -1e30f;
#pragma unroll
    for (int i = 0; i < 4; ++i)
        m = fmaxf(m, fmaxf(fmaxf(v[i].x, v[i].y), fmaxf(v[i].z, v[i].w)));
#pragma unroll
    for (int off = 32; off; off >>= 1) m = fmaxf(m, __shfl_xor(m, off));
    __shared__ float redm[4];
    if ((t & 63) == 0) redm[t >> 6] = m;
    __syncthreads();
    m = fmaxf(fmaxf(redm[0], redm[1]), fmaxf(redm[2], redm[3]));

    float s = 0.f;
#pragma unroll
    for (int i = 0; i < 4; ++i) {
        v[i].x = __expf(v[i].x - m); v[i].y = __expf(v[i].y - m);
        v[i].z = __expf(v[i].z - m); v[i].w = __expf(v[i].w - m);
        s += v[i].x + v[i].y + v[i].z + v[i].w;
    }
#pragma unroll
    for (int off = 32; off; off >>= 1) s += __shfl_xor(s, off);
    __shared__ float reds[4];
    if ((t & 63) == 0) reds[t >> 6] = s;
    __syncthreads();
    s = reds[0] + reds[1] + reds[2] + reds[3];
    const float inv = 1.0f / s;

    u16* pw = (u16*)p;
#pragma unroll
    for (int i = 0; i < 4; ++i) {
        u16x4 w;
        w[0] = f2bf(v[i].x * inv); w[1] = f2bf(v[i].y * inv);
        w[2] = f2bf(v[i].z * inv); w[3] = f2bf(v[i].w * inv);
        *(u16x4*)(pw + 4 * (t + i * 256)) = w;
    }
}

extern "C" void kernel_launch(void* const* d_in, const int* in_sizes, int n_in,
                              void* d_out, int out_size, void* d_ws, size_t ws_size,
                              hipStream_t stream)
{
    const float* x   = (const float*)d_in[0];   // [4,2048,1024] fp32
    const float* mem = (const float*)d_in[1];   // [4,4096,512]  fp32
    const float* Wq  = (const float*)d_in[2];   // [512,1024]    fp32
    const float* bq  = (const float*)d_in[3];   // [512]         fp32
    const float* Wm  = (const float*)d_in[4];   // [1024,512]    fp32
    const float* bm  = (const float*)d_in[5];   // [1024]        fp32

    // d_out: fp32, 16,777,216 floats = 64MB. out0 = [0,32MB) <- x; out1 = [32,64MB).
    // Scratch schedule (all dead before the region's final producer writes):
    //   [ 0MB,16MB)  Qf : fp32 Q [8192,512]; after each batch's PV, that batch's
    //                     rows' first 1KB overwritten by bf16 Att (row stride 1024 u16)
    //   [16MB,20MB)  MemT: current batch's mem^T [512,4096] bf16
    //   [20MB,52MB)  Sc : fp32 scores [2048,4096] (full batch); softmax rewrites each
    //                     16KB row-slot's first 8KB as bf16 weights. Overlaps out1's
    //                     [32MB,...) — dead before the final GEMM writes out1.
    char* base = (char*)d_out;
    float* Qf   = (float*)base;
    u16*   MemT = (u16*)(base + (16ll << 20));
    float* Sc   = (float*)(base + (20ll << 20));
    float* out1 = (float*)d_out + 8388608ll;

    // Qf = x @ Wq^T + bq   [8192,512], K=1024, split-bf16 fp32-precision
    gemm_nt3<<<dim3(512 / 128, 8192 / 128), 256, 0, stream>>>(
        x, Wq, bq, Qf, 1024, 1024, 1024, 512);

    for (int b = 0; b < 4; ++b) {
        const float* Mb = mem + (long long)b * 4096 * 512;
        float* Qb = Qf + (long long)b * 2048 * 512;

        // MemT = bf16(Mb^T)  [512,4096]
        transpose_mem<<<dim3(8, 64), 256, 0, stream>>>(Mb, MemT);

        // Sc = Qb @ Mb^T   [2048,4096], K=512, split-bf16 fp32-precision
        gemm_nt3<<<dim3(4096 / 128, 2048 / 128), 256, 0, stream>>>(
            Qb, Mb, nullptr, Sc, 512, 512, 512, 4096);

        // softmax rows -> bf16 weights in place
        softmax_rows<<<dim3(2048), 256, 0, stream>>>(Sc);

        // Att_b = W @ MemT^T  [2048,512], K=4096 (A rows strided 8192 u16)
        // writes bf16 att into the dead Q rows (row stride 1024 u16)
        gemm_nt<u16, u16, false><<<dim3(512 / 128, 2048 / 128), 256, 0, stream>>>(
            (const u16*)Sc, MemT, nullptr, (u16*)Qb, 4096, 8192, 4096, 1024);
    }

    // out1 = Att @ Wm^T + bm   [8192,1024], K=512
    // A = bf16 Att rows at stride 1024 u16  ==> lda MUST be 1024 (round-6 bug: was 512)
    gemm_nt<u16, float, true><<<dim3(1024 / 128, 8192 / 128), 256, 0, stream>>>(
        (const u16*)Qf, Wm, bm, out1, 512, 1024, 512, 1024);

    // out0 = x (exact fp32 copy; overwrites dead Qf/MemT/Sc scratch). Must be last.
    hipMemcpyAsync(d_out, x, 8192ll * 1024 * 4, hipMemcpyDeviceToDevice, stream);
}